// Round 4
// baseline (357.854 us; speedup 1.0000x reference)
//
#include <hip/hip_runtime.h>
#include <math.h>

#define EPS 1e-5f

typedef _Float16 half4 __attribute__((ext_vector_type(4)));
typedef _Float16 half8 __attribute__((ext_vector_type(8)));
typedef float floatx4 __attribute__((ext_vector_type(4)));

#if __has_builtin(__builtin_amdgcn_exp2f)
#define EXP2F __builtin_amdgcn_exp2f
#else
#define EXP2F exp2f
#endif

static __device__ __forceinline__ float fast_rcp(float x) {
#if __has_builtin(__builtin_amdgcn_rcpf)
  return __builtin_amdgcn_rcpf(x);
#else
  return 1.f / x;
#endif
}

static __device__ __forceinline__ half4 pack4(float a, float b, float c, float d) {
#if __has_builtin(__builtin_amdgcn_cvt_pkrtz)
  auto lo = __builtin_amdgcn_cvt_pkrtz(a, b);
  auto hi = __builtin_amdgcn_cvt_pkrtz(c, d);
  half4 h;
  h[0] = (_Float16)lo[0];
  h[1] = (_Float16)lo[1];
  h[2] = (_Float16)hi[0];
  h[3] = (_Float16)hi[1];
  return h;
#else
  half4 h;
  h[0] = (_Float16)a; h[1] = (_Float16)b; h[2] = (_Float16)c; h[3] = (_Float16)d;
  return h;
#endif
}

// ---------------------------------------------------------------------------
// Kw: W precompute. w16[o][c] = wq[o][c] * qkv_sc[o] * (q-ch ? s_scale/4*lg2e : 1)
//     bis[o] = (qb - qm*sc) * (same factor).  grid=64, block=512.
// ---------------------------------------------------------------------------
__global__ void wprep_k(const float* __restrict__ wq,
                        const float* __restrict__ qg, const float* __restrict__ qb,
                        const float* __restrict__ qm, const float* __restrict__ qv,
                        const float* __restrict__ sg, const float* __restrict__ svv,
                        _Float16* __restrict__ w16, float* __restrict__ bis) {
  int idx = blockIdx.x * 512 + threadIdx.x;  // 0..32767
  int o = idx >> 7, c = idx & 127;
  int g = o >> 5, ch = o & 31;
  float sc = qg[o] * rsqrtf(qv[o] + EPS);
  float bi = qb[o] - qm[o] * sc;
  if (ch < 8) {
    float al = sg[g] * rsqrtf(svv[g] + EPS) * (0.25f * 1.44269504f);
    sc *= al;
    bi *= al;
  }
  w16[idx] = (_Float16)(wq[idx] * sc);
  if (c == 0) bis[o] = bi;
}

// ---------------------------------------------------------------------------
// K1: fused transpose-free GEMM. Block = (n, h): C[o=0..255][w=0..127] for the
// fixed (n,h) plane:  qkvL[n][o][h][w] = fp16( sum_c w16[o][c]*x[n][c][h][w] + bis[o] )
// x rows (c, fixed h) are CONTIGUOUS in w -> float4 coalesced staging into
// Xs[c][w] fp16 (no transpose anywhere; old K0 + the 96MB xt2 roundtrip die).
// A-frags stream from L2-resident w16 (64KB); B-frags gathered from Xs via
// ds_read_b16 (k-minor gather; bank-checked 2-way worst = free).
// 512 thr = 8 waves: wave tile 64o x 64w (m0=(wv&3)*64, n0=(wv>>2)*64).
// x read EXACTLY once across the grid; HBM = 64MB in + 64MB out.
// ---------------------------------------------------------------------------
__global__ void __launch_bounds__(512, 4) gemm_qkv_k(
    const float* __restrict__ x, const _Float16* __restrict__ w16,
    const float* __restrict__ bis, _Float16* __restrict__ qkvL) {
  __shared__ _Float16 Xs[128][132];
  int bid = blockIdx.x;
  int n = bid >> 7;
  int ht = bid & 127;
  int t = threadIdx.x;

  {  // stage: x[n][c][ht][w] fp32 -> Xs[c][w] fp16, coalesced float4
    const float* xb = x + (size_t)n * 2097152 + (size_t)ht * 128;
    int w4 = (t & 31) * 4;
    int cs = t >> 5;  // 0..15
#pragma unroll
    for (int cc = cs; cc < 128; cc += 16) {
      float4 v = *(const float4*)(xb + (size_t)cc * 16384 + w4);
      *(half4*)(&Xs[cc][w4]) = pack4(v.x, v.y, v.z, v.w);
    }
  }
  __syncthreads();

  int wv = t >> 6;
  int lane = t & 63;
  int ln = lane & 15;
  int q4 = lane >> 4;
  int m0 = (wv & 3) * 64;   // o-base
  int n0 = (wv >> 2) * 64;  // w-base

  floatx4 acc[4][4];
#pragma unroll
  for (int mt = 0; mt < 4; mt++)
#pragma unroll
    for (int nt = 0; nt < 4; nt++)
#pragma unroll
      for (int r = 0; r < 4; r++) acc[mt][nt][r] = 0.f;

#pragma unroll
  for (int k0 = 0; k0 < 128; k0 += 32) {
    half8 af[4], bf[4];
#pragma unroll
    for (int mt = 0; mt < 4; mt++)
      af[mt] = *(const half8*)(w16 + (size_t)(m0 + mt * 16 + ln) * 128 + k0 + q4 * 8);
#pragma unroll
    for (int nt = 0; nt < 4; nt++)
#pragma unroll
      for (int e = 0; e < 8; e++)
        bf[nt][e] = Xs[k0 + q4 * 8 + e][n0 + nt * 16 + ln];
#pragma unroll
    for (int mt = 0; mt < 4; mt++)
#pragma unroll
      for (int nt = 0; nt < 4; nt++)
        acc[mt][nt] = __builtin_amdgcn_mfma_f32_16x16x32_f16(af[mt], bf[nt], acc[mt][nt], 0, 0, 0);
  }

  _Float16* outb = qkvL + (size_t)n * 4194304 + (size_t)ht * 128;
#pragma unroll
  for (int mt = 0; mt < 4; mt++) {
    float4 bi4 = *(const float4*)(bis + m0 + mt * 16 + q4 * 4);
#pragma unroll
    for (int r = 0; r < 4; r++) {
      int o = m0 + mt * 16 + q4 * 4 + r;
      float bi = (r == 0) ? bi4.x : (r == 1) ? bi4.y : (r == 2) ? bi4.z : bi4.w;
#pragma unroll
      for (int nt = 0; nt < 4; nt++) {
        int w = n0 + nt * 16 + ln;
        outb[(size_t)o * 16384 + w] = (_Float16)(acc[mt][nt][r] + bi);
      }
    }
  }
}

// ---------------------------------------------------------------------------
// K2: MFMA attention + out-BN + final transpose -> fp32 out.
// Reads qkvL[n][o][h][w] (w-minor). Block = (n,g,wt): 512 thr = 8 waves, wave
// wv owns w = wt*8+wv; q/k/v gathered as 2B scalars (L2/L3-resident; the 16
// wt-blocks of one (n,g) are XCD-grouped so K/V stay in one L2).
// Softmax/PV pipeline unchanged from verified r3 (max tree + shfl, exp2-domain
// logits, ones-MFMA row sums, two-phase plds reuse).
// olds halved to [16c][64h][8w] (16KB) with a double-pass epilogue ->
// LDS 34KB -> 4 blocks/CU; grid 1024 = exactly one residency round.
// olds swizzle: idx ^= (q4-bits)<<3 -> write conflicts 8-way -> 2-way (free).
// ---------------------------------------------------------------------------
__global__ void __launch_bounds__(512, 4) attn_mfma_fused_kernel(
    const _Float16* __restrict__ qkvL,
    const float* __restrict__ og, const float* __restrict__ obt,
    const float* __restrict__ om, const float* __restrict__ ov,
    float* __restrict__ out) {
  __shared__ _Float16 olds[8192];     // [c][h64][w8] swizzled, 16KB
  __shared__ _Float16 plds[8][1152];  // per-wave P half-tile [16][72], 18KB
  int bid = blockIdx.x;
  // XCD-grouping: the 16 wt-blocks of one (n,g) land on one XCD (bid%8 model)
  int grp = (bid & 7) * 8 + ((bid >> 3) >> 4);  // 0..63 = (n,g)
  int wt = (bid >> 3) & 15;
  int nn = grp >> 3;
  int g = grp & 7;
  int t = threadIdx.x;
  int wv = t >> 6;
  int lane = t & 63;
  int ln = lane & 15;
  int q4 = lane >> 4;

  // out-BN coeffs for this lane's O rows c = q4*4 + r
  float osc[4], obi[4];
#pragma unroll
  for (int r = 0; r < 4; r++) {
    int oc = g * 16 + q4 * 4 + r;
    float s0 = og[oc] * rsqrtf(ov[oc] + EPS);
    osc[r] = s0;
    obi[r] = obt[oc] - om[oc] * s0;
  }

  half8 onesv;
#pragma unroll
  for (int i = 0; i < 8; i++) onesv[i] = (_Float16)1.0f;

  _Float16* pw = &plds[wv][0];
  int w = wt * 8 + wv;
  const _Float16* base = qkvL + (size_t)nn * 4194304 + (size_t)(g * 32) * 16384 + w;

  // k fragments (A-operand): kf[jt][jj] = K[ch=jj][j=jt*16+ln] at fixed w
  half8 kf[8];
#pragma unroll
  for (int jt = 0; jt < 8; jt++)
#pragma unroll
    for (int jj = 0; jj < 8; jj++)
      kf[jt][jj] = base[(8 + jj) * 16384 + (jt * 16 + ln) * 128];

  // v fragments (A-operand for PV): lane ln = c, 8 j's per quad
  half8 vf[4];
#pragma unroll
  for (int ks = 0; ks < 4; ks++)
#pragma unroll
    for (int e = 0; e < 8; e++)
      vf[ks][e] = base[(16 + ln) * 16384 + (ks * 32 + q4 * 8 + e) * 128];

  for (int half = 0; half < 2; half++) {
#pragma unroll
    for (int s4 = 0; s4 < 4; s4++) {
      int st8 = half * 4 + s4;
      // q fragment (B-operand) for i-strip st8 (pre-scaled log2-domain logits)
      half8 qf;
#pragma unroll
      for (int jj = 0; jj < 8; jj++)
        qf[jj] = base[jj * 16384 + (st8 * 16 + ln) * 128];

      // S^T tiles: C[j][i], 8 j-tiles
      floatx4 stt[8];
#pragma unroll
      for (int jt = 0; jt < 8; jt++) {
        floatx4 z = {0.f, 0.f, 0.f, 0.f};
        stt[jt] = __builtin_amdgcn_mfma_f32_16x16x32_f16(kf[jt], qf, z, 0, 0, 0);
      }

      // column max over j + cross-quad reduce
      float mx = fmaxf(stt[0][0], stt[0][1]);
      mx = fmaxf(fmaxf(mx, stt[0][2]), stt[0][3]);
#pragma unroll
      for (int jt = 1; jt < 8; jt++) {
        mx = fmaxf(fmaxf(mx, stt[jt][0]), stt[jt][1]);
        mx = fmaxf(fmaxf(mx, stt[jt][2]), stt[jt][3]);
      }
      mx = fmaxf(mx, __shfl_xor(mx, 16));
      mx = fmaxf(mx, __shfl_xor(mx, 32));

      floatx4 oacc = {0.f, 0.f, 0.f, 0.f};
      floatx4 lacc = {0.f, 0.f, 0.f, 0.f};

      // ---- phase 0: j tiles 0..3 -> P slice, PV k-slices 0..1 ----
#pragma unroll
      for (int jt = 0; jt < 4; jt++) {
        half4 h = pack4(EXP2F(stt[jt][0] - mx), EXP2F(stt[jt][1] - mx),
                        EXP2F(stt[jt][2] - mx), EXP2F(stt[jt][3] - mx));
        *(half4*)(&pw[ln * 72 + jt * 16 + q4 * 4]) = h;
      }
#pragma unroll
      for (int ks = 0; ks < 2; ks++) {
        half8 pf = *(const half8*)(&pw[ln * 72 + ks * 32 + q4 * 8]);
        oacc = __builtin_amdgcn_mfma_f32_16x16x32_f16(vf[ks], pf, oacc, 0, 0, 0);
        lacc = __builtin_amdgcn_mfma_f32_16x16x32_f16(onesv, pf, lacc, 0, 0, 0);
      }
      // ---- phase 1: j tiles 4..7 reuse the same LDS slice, PV k-slices 2..3 ----
#pragma unroll
      for (int jt = 0; jt < 4; jt++) {
        half4 h = pack4(EXP2F(stt[jt + 4][0] - mx), EXP2F(stt[jt + 4][1] - mx),
                        EXP2F(stt[jt + 4][2] - mx), EXP2F(stt[jt + 4][3] - mx));
        *(half4*)(&pw[ln * 72 + jt * 16 + q4 * 4]) = h;
      }
#pragma unroll
      for (int ks = 0; ks < 2; ks++) {
        half8 pf = *(const half8*)(&pw[ln * 72 + ks * 32 + q4 * 8]);
        oacc = __builtin_amdgcn_mfma_f32_16x16x32_f16(vf[ks + 2], pf, oacc, 0, 0, 0);
        lacc = __builtin_amdgcn_mfma_f32_16x16x32_f16(onesv, pf, lacc, 0, 0, 0);
      }

      // normalize + out-BN -> staged fp16 in olds (swizzled), hloc = local h
      float invl = fast_rcp(lacc[0]);
      int hloc = s4 * 16 + ln;
#pragma unroll
      for (int r = 0; r < 4; r++) {
        int c = q4 * 4 + r;
        int idx = (c << 9) + (hloc << 3) + wv;
        idx ^= ((c >> 2) & 3) << 3;  // spread quads across banks
        olds[idx] = (_Float16)fmaf(oacc[r] * invl, osc[r], obi[r]);
      }
    }

    __syncthreads();
    // cooperative store of this h-half: out[n][g*16+c][half*64+h][wt*8+w]
    float* outp = out + ((size_t)nn * 128 + g * 16) * 16384 + (size_t)half * 8192 + wt * 8;
#pragma unroll
    for (int idx2 = t; idx2 < 2048; idx2 += 512) {
      int w4 = idx2 & 1;
      int hh = (idx2 >> 1) & 63;
      int c = idx2 >> 7;
      int hidx = (c << 9) + (hh << 3) + w4 * 4;
      hidx ^= ((c >> 2) & 3) << 3;
      half4 v = *(const half4*)(&olds[hidx]);
      float4 f;
      f.x = (float)v[0];
      f.y = (float)v[1];
      f.z = (float)v[2];
      f.w = (float)v[3];
      *(float4*)(outp + (size_t)c * 16384 + (size_t)hh * 128 + w4 * 4) = f;
    }
    if (half == 0) __syncthreads();
  }
}

// ---------------------------------------------------------------------------
extern "C" void kernel_launch(void* const* d_in, const int* in_sizes, int n_in,
                              void* d_out, int out_size, void* d_ws, size_t ws_size,
                              hipStream_t stream) {
  const float* x  = (const float*)d_in[0];
  const float* wq = (const float*)d_in[1];
  const float* qg = (const float*)d_in[2];
  const float* qb = (const float*)d_in[3];
  const float* qm = (const float*)d_in[4];
  const float* qv = (const float*)d_in[5];
  const float* sg = (const float*)d_in[6];
  const float* sb = (const float*)d_in[7];
  const float* sm = (const float*)d_in[8];
  const float* sv = (const float*)d_in[9];
  const float* og = (const float*)d_in[10];
  const float* ob = (const float*)d_in[11];
  const float* om = (const float*)d_in[12];
  const float* ov = (const float*)d_in[13];
  float* out = (float*)d_out;
  (void)sb;
  (void)sm;

  // workspace: qkvL 64MB | w16 64KB | bis 1KB
  _Float16* qkvL = (_Float16*)d_ws;
  _Float16* w16 = qkvL + (size_t)8 * 256 * 16384;
  float* bis = (float*)(w16 + 256 * 128);

  // Kw: W precompute with folded BN/softmax scales
  wprep_k<<<64, 512, 0, stream>>>(wq, qg, qb, qm, qv, sg, sv, w16, bis);
  // K1: transpose-free fused GEMM + bias -> qkvL[n][o][h][w] fp16
  gemm_qkv_k<<<1024, 512, 0, stream>>>(x, w16, bis, qkvL);
  // K2: MFMA attention + out-BN + final transpose -> out fp32 (N,O,H,W)
  attn_mfma_fused_kernel<<<1024, 512, 0, stream>>>(qkvL, og, ob, om, ov, out);
}

// Round 6
// 238.634 us; speedup vs baseline: 1.4996x; 1.4996x over previous
//
#include <hip/hip_runtime.h>
#include <math.h>

#define EPS 1e-5f

typedef _Float16 half4 __attribute__((ext_vector_type(4)));
typedef _Float16 half8 __attribute__((ext_vector_type(8)));
typedef float floatx4 __attribute__((ext_vector_type(4)));

#if __has_builtin(__builtin_amdgcn_exp2f)
#define EXP2F __builtin_amdgcn_exp2f
#else
#define EXP2F exp2f
#endif

static __device__ __forceinline__ float fast_rcp(float x) {
#if __has_builtin(__builtin_amdgcn_rcpf)
  return __builtin_amdgcn_rcpf(x);
#else
  return 1.f / x;
#endif
}

static __device__ __forceinline__ half4 pack4(float a, float b, float c, float d) {
#if __has_builtin(__builtin_amdgcn_cvt_pkrtz)
  auto lo = __builtin_amdgcn_cvt_pkrtz(a, b);
  auto hi = __builtin_amdgcn_cvt_pkrtz(c, d);
  half4 h;
  h[0] = (_Float16)lo[0];
  h[1] = (_Float16)lo[1];
  h[2] = (_Float16)hi[0];
  h[3] = (_Float16)hi[1];
  return h;
#else
  half4 h;
  h[0] = (_Float16)a; h[1] = (_Float16)b; h[2] = (_Float16)c; h[3] = (_Float16)d;
  return h;
#endif
}

// ---------------------------------------------------------------------------
// K0: x (N,C,H,W) fp32 -> xt2[b=(n,w)][i=h][c] fp16.
// Per (n,h): transpose 128x128 (c,w) -> (w,c). grid=(1024, 2, 2), block=256.
// Sideband (blocks x<256,y=0,z=0): W -> w16 fp16 with BOTH BN scales folded:
//   w16[o][c] = wq[o][c] * qkv_sc[o] * (q-channel ? s_scale/4*log2e : 1)
//   bis[o]    = (qb - qm*sc) * (same factor)
// => K1 is GEMM+bias only; attn logits come out pre-scaled in log2 domain.
// ---------------------------------------------------------------------------
__global__ void transpose_cvt_k(const float* __restrict__ x, _Float16* __restrict__ xt2,
                                const float* __restrict__ wq,
                                const float* __restrict__ qg, const float* __restrict__ qb,
                                const float* __restrict__ qm, const float* __restrict__ qv,
                                const float* __restrict__ sg, const float* __restrict__ svv,
                                _Float16* __restrict__ w16, float* __restrict__ bis) {
  if (blockIdx.y == 0 && blockIdx.z == 0 && blockIdx.x < 256) {
    int tt = threadIdx.x;
    int o = blockIdx.x;
    if (tt < 128) {
      int g = o >> 5, ch = o & 31;
      float sc = qg[o] * rsqrtf(qv[o] + EPS);
      float bi = qb[o] - qm[o] * sc;
      if (ch < 8) {
        float al = sg[g] * rsqrtf(svv[g] + EPS) * (0.25f * 1.44269504f);
        sc *= al;
        bi *= al;
      }
      w16[o * 128 + tt] = (_Float16)(wq[o * 128 + tt] * sc);
      if (tt == 0) bis[o] = bi;
    }
  }

  __shared__ float tile[64][65];
  int nh = blockIdx.x;
  int n = nh >> 7, h = nh & 127;
  int c0 = blockIdx.y * 64, w0 = blockIdx.z * 64;
  const float* src = x + (size_t)n * 2097152 + (size_t)h * 128;  // (c,w): src[c*16384 + w]
  _Float16* dst = xt2 + (size_t)n * 2097152 + (size_t)h * 128;   // (w,c): dst[w*16384 + c]
  int lane = threadIdx.x & 63;
  int tr = threadIdx.x >> 6;
#pragma unroll
  for (int rr = tr; rr < 64; rr += 4)
    tile[rr][lane] = src[(size_t)(c0 + rr) * 16384 + w0 + lane];
  __syncthreads();
#pragma unroll
  for (int cc = tr; cc < 64; cc += 4)
    dst[(size_t)(w0 + cc) * 16384 + c0 + lane] = (_Float16)tile[lane][cc];
}

// ---------------------------------------------------------------------------
// K1: qkv16[b][o][i] = fp16( sum_c w16[o][c]*xt2[b][i][c] + bis[o] )
// LDS-FREE dual-stream: af from L2-hot w16 (64KB total), bf straight from
// xt2 global as 16B/lane 64B-coalesced segments, each read once per block.
// No stage, no barrier (r3's stage+barrier serialized ~1/3 of block life;
// m233 pattern). Occupancy VGPR-bound: ~100 VGPR < 128 @ (256,4) -> 16 w/CU.
// XCD oh-pairing kept: the two oh-halves of one b land on the same XCD so
// the second pass over xt2[b] hits L2.
// ---------------------------------------------------------------------------
__global__ void __launch_bounds__(256, 4) qkv_mfma_kernel(
    const _Float16* __restrict__ xt2, const _Float16* __restrict__ w16,
    const float* __restrict__ bis, _Float16* __restrict__ qkv16) {
  int d = blockIdx.x;
  int xcd = d & 7;
  int slot = d >> 3;
  int b = (slot >> 1) * 8 + xcd;  // bijective over 0..1023 (2048 blocks /2)
  int oh = slot & 1;
  int t = threadIdx.x;
  int wv = t >> 6;
  int lane = t & 63;
  int m0 = (wv & 1) * 64;
  int n0 = (wv >> 1) * 64;
  int ln = lane & 15;
  int q4 = lane >> 4;

  const _Float16* wb = w16 + (size_t)oh * 16384;
  const _Float16* xb = xt2 + (size_t)b * 16384;

  floatx4 acc[4][4];
#pragma unroll
  for (int mt = 0; mt < 4; mt++)
#pragma unroll
    for (int nt = 0; nt < 4; nt++)
#pragma unroll
      for (int r = 0; r < 4; r++) acc[mt][nt][r] = 0.f;

#pragma unroll
  for (int k0 = 0; k0 < 128; k0 += 32) {
    half8 af[4], bf[4];
#pragma unroll
    for (int mt = 0; mt < 4; mt++)
      af[mt] = *(const half8*)(wb + (size_t)(m0 + mt * 16 + ln) * 128 + k0 + q4 * 8);
#pragma unroll
    for (int nt = 0; nt < 4; nt++)
      bf[nt] = *(const half8*)(xb + (size_t)(n0 + nt * 16 + ln) * 128 + k0 + q4 * 8);
#pragma unroll
    for (int mt = 0; mt < 4; mt++)
#pragma unroll
      for (int nt = 0; nt < 4; nt++)
        acc[mt][nt] = __builtin_amdgcn_mfma_f32_16x16x32_f16(af[mt], bf[nt], acc[mt][nt], 0, 0, 0);
  }

  _Float16* outb = qkv16 + (size_t)b * 32768 + (size_t)oh * 16384;
#pragma unroll
  for (int mt = 0; mt < 4; mt++) {
    float4 bi4 = *(const float4*)(bis + oh * 128 + m0 + mt * 16 + q4 * 4);
#pragma unroll
    for (int r = 0; r < 4; r++) {
      int o_l = m0 + mt * 16 + q4 * 4 + r;
      float bi = (r == 0) ? bi4.x : (r == 1) ? bi4.y : (r == 2) ? bi4.z : bi4.w;
#pragma unroll
      for (int nt = 0; nt < 4; nt++) {
        int i = n0 + nt * 16 + ln;
        outb[(size_t)o_l * 128 + i] = (_Float16)(acc[mt][nt][r] + bi);
      }
    }
  }
}

// ---------------------------------------------------------------------------
// K2: MFMA attention + out-BN + final transpose -> fp32 out. Block = (n,g,wt):
// 512 thr = 8 waves, wave wv owns w = wt*8+wv. Per-wave algorithm as verified:
// S^T = mfma(k^T, q^T), quad-replicated K=8 (the /4, s_scale, log2e are
// pre-folded into q via w16). Softmax over j: max tree + shfl_xor(16,32);
// exp2 direct (log2-domain logits); row sums via parallel ones-A MFMA.
// P halved: PV in two phases reusing one 16x72 LDS slice (wave-ordered DS).
// LDS 51.2KB -> 3 blocks/CU ceiling; launch_bounds(512,4) (NOT 6: round-2
// showed (512,6) forces VGPR=40 -> scratch spill, FETCH 275MB, 137us).
// olds staging XOR-swizzled: 8-way -> 4-way write conflict.
// [Byte-identical to round-3's verified 62us kernel.]
// ---------------------------------------------------------------------------
__global__ void __launch_bounds__(512, 4) attn_mfma_fused_kernel(
    const _Float16* __restrict__ qkv16,
    const float* __restrict__ og, const float* __restrict__ obt,
    const float* __restrict__ om, const float* __restrict__ ov,
    float* __restrict__ out) {
  __shared__ _Float16 olds[16384];    // [c][h][w8] swizzled, 32KB
  __shared__ _Float16 plds[8][1152];  // per-wave P half-tile [16][72], 18KB
  int bid = blockIdx.x;
  int nn = bid >> 7;
  int g = (bid >> 4) & 7;
  int wt = bid & 15;
  int t = threadIdx.x;
  int wv = t >> 6;
  int lane = t & 63;
  int ln = lane & 15;
  int q4 = lane >> 4;

  // out-BN coeffs for this lane's O rows c = q4*4 + r
  float osc[4], obi[4];
#pragma unroll
  for (int r = 0; r < 4; r++) {
    int oc = g * 16 + q4 * 4 + r;
    float s0 = og[oc] * rsqrtf(ov[oc] + EPS);
    osc[r] = s0;
    obi[r] = obt[oc] - om[oc] * s0;
  }

  half8 onesv;
#pragma unroll
  for (int i = 0; i < 8; i++) onesv[i] = (_Float16)1.0f;

  _Float16* pw = &plds[wv][0];
  int b = nn * 128 + wt * 8 + wv;
  const _Float16* base = qkv16 + (size_t)b * 32768 + (size_t)g * 4096;
  const _Float16* kb = base + 1024;
  const _Float16* vb = base + 2048;

  // k fragments (A-operand), all j-tiles, channels replicated per quad
  half8 kf[8];
#pragma unroll
  for (int jt = 0; jt < 8; jt++)
#pragma unroll
    for (int jj = 0; jj < 8; jj++)
      kf[jt][jj] = kb[jj * 128 + jt * 16 + ln];

  // v fragments (A-operand for PV): lane&15 = c, 8 consecutive j per quad
  half8 vf[4];
#pragma unroll
  for (int ks = 0; ks < 4; ks++)
    vf[ks] = *(const half8*)(vb + (size_t)ln * 128 + ks * 32 + q4 * 8);

  for (int st8 = 0; st8 < 8; st8++) {
    // q fragment (B-operand) for i-strip st8 (pre-scaled: log2-domain logits)
    half8 qf;
#pragma unroll
    for (int jj = 0; jj < 8; jj++)
      qf[jj] = base[jj * 128 + st8 * 16 + ln];

    // S^T tiles: C[j][i], 8 j-tiles
    floatx4 stt[8];
#pragma unroll
    for (int jt = 0; jt < 8; jt++) {
      floatx4 z = {0.f, 0.f, 0.f, 0.f};
      stt[jt] = __builtin_amdgcn_mfma_f32_16x16x32_f16(kf[jt], qf, z, 0, 0, 0);
    }

    // column max over j (v_max3-friendly tree) + cross-quad reduce
    float mx = fmaxf(stt[0][0], stt[0][1]);
    mx = fmaxf(fmaxf(mx, stt[0][2]), stt[0][3]);
#pragma unroll
    for (int jt = 1; jt < 8; jt++) {
      mx = fmaxf(fmaxf(mx, stt[jt][0]), stt[jt][1]);
      mx = fmaxf(fmaxf(mx, stt[jt][2]), stt[jt][3]);
    }
    mx = fmaxf(mx, __shfl_xor(mx, 16));
    mx = fmaxf(mx, __shfl_xor(mx, 32));

    floatx4 oacc = {0.f, 0.f, 0.f, 0.f};
    floatx4 lacc = {0.f, 0.f, 0.f, 0.f};

    // ---- phase 0: j tiles 0..3 -> P slice, PV k-slices 0..1 ----
#pragma unroll
    for (int jt = 0; jt < 4; jt++) {
      half4 h = pack4(EXP2F(stt[jt][0] - mx), EXP2F(stt[jt][1] - mx),
                      EXP2F(stt[jt][2] - mx), EXP2F(stt[jt][3] - mx));
      *(half4*)(&pw[ln * 72 + jt * 16 + q4 * 4]) = h;
    }
#pragma unroll
    for (int ks = 0; ks < 2; ks++) {
      half8 pf = *(const half8*)(&pw[ln * 72 + ks * 32 + q4 * 8]);
      oacc = __builtin_amdgcn_mfma_f32_16x16x32_f16(vf[ks], pf, oacc, 0, 0, 0);
      lacc = __builtin_amdgcn_mfma_f32_16x16x32_f16(onesv, pf, lacc, 0, 0, 0);
    }
    // ---- phase 1: j tiles 4..7 reuse the same LDS slice, PV k-slices 2..3 ----
#pragma unroll
    for (int jt = 0; jt < 4; jt++) {
      half4 h = pack4(EXP2F(stt[jt + 4][0] - mx), EXP2F(stt[jt + 4][1] - mx),
                      EXP2F(stt[jt + 4][2] - mx), EXP2F(stt[jt + 4][3] - mx));
      *(half4*)(&pw[ln * 72 + jt * 16 + q4 * 4]) = h;
    }
#pragma unroll
    for (int ks = 0; ks < 2; ks++) {
      half8 pf = *(const half8*)(&pw[ln * 72 + ks * 32 + q4 * 8]);
      oacc = __builtin_amdgcn_mfma_f32_16x16x32_f16(vf[ks + 2], pf, oacc, 0, 0, 0);
      lacc = __builtin_amdgcn_mfma_f32_16x16x32_f16(onesv, pf, lacc, 0, 0, 0);
    }

    // normalize + out-BN -> staged fp16 in olds (swizzled)
    float invl = fast_rcp(lacc[0]);
#pragma unroll
    for (int r = 0; r < 4; r++) {
      int c = q4 * 4 + r;
      int idx = (c << 10) + ((st8 * 16 + ln) << 3) + wv;
      idx ^= (q4 & 3) << 2;
      olds[idx] = (_Float16)fmaf(oacc[r] * invl, osc[r], obi[r]);
    }
  }

  __syncthreads();

  // cooperative transposed store: out[n][g*16+c][h][wt*8 + w], float4-of-w
  float* outp = out + ((size_t)nn * 128 + g * 16) * 16384 + wt * 8;
#pragma unroll
  for (int idx = t; idx < 4096; idx += 512) {
    int w4 = idx & 1;
    int h = (idx >> 1) & 127;
    int c = idx >> 8;
    int hidx = (c << 10) + (h << 3) + w4 * 4;
    hidx ^= ((c >> 2) & 3) << 2;
    half4 v = *(const half4*)(&olds[hidx]);
    float4 f;
    f.x = (float)v[0];
    f.y = (float)v[1];
    f.z = (float)v[2];
    f.w = (float)v[3];
    *(float4*)(outp + (size_t)c * 16384 + (size_t)h * 128 + w4 * 4) = f;
  }
}

// ---------------------------------------------------------------------------
extern "C" void kernel_launch(void* const* d_in, const int* in_sizes, int n_in,
                              void* d_out, int out_size, void* d_ws, size_t ws_size,
                              hipStream_t stream) {
  const float* x  = (const float*)d_in[0];
  const float* wq = (const float*)d_in[1];
  const float* qg = (const float*)d_in[2];
  const float* qb = (const float*)d_in[3];
  const float* qm = (const float*)d_in[4];
  const float* qv = (const float*)d_in[5];
  const float* sg = (const float*)d_in[6];
  const float* sb = (const float*)d_in[7];
  const float* sm = (const float*)d_in[8];
  const float* sv = (const float*)d_in[9];
  const float* og = (const float*)d_in[10];
  const float* ob = (const float*)d_in[11];
  const float* om = (const float*)d_in[12];
  const float* ov = (const float*)d_in[13];
  float* out = (float*)d_out;
  (void)sb;
  (void)sm;

  // workspace: qkv16 64MB | xt2 32MB | w16 64KB | bis 1KB
  _Float16* qkv16 = (_Float16*)d_ws;
  _Float16* xt2 = qkv16 + (size_t)1024 * 256 * 128;
  _Float16* w16 = xt2 + (size_t)1024 * 128 * 128;
  float* bis = (float*)(w16 + 256 * 128);

  // K0: x -> xt2[b][i][c] fp16 (+ sideband: W/bias precompute with folded scales)
  transpose_cvt_k<<<dim3(1024, 2, 2), 256, 0, stream>>>(x, xt2, wq, qg, qb, qm, qv,
                                                        sg, sv, w16, bis);
  // K1: LDS-free dual-stream f16 MFMA GEMM + bias -> qkv16[b][o][i] fp16
  qkv_mfma_kernel<<<2048, 256, 0, stream>>>(xt2, w16, bis, qkv16);
  // K2: MFMA attention + out-BN + final transpose -> out fp32 (N,O,H,W)
  attn_mfma_fused_kernel<<<1024, 512, 0, stream>>>(qkv16, og, ob, om, ov, out);
}